// Round 9
// baseline (364.084 us; speedup 1.0000x reference)
//
#include <hip/hip_runtime.h>
#include <hip/hip_bf16.h>

typedef unsigned short u16;

#define T_NODES 32768
#define NPG 1024
#define BGR 32
#define D 64
#define FIN 8
#define CSR_BLOCKS 64

// ---- bf16 <-> f32 (shift is the exact bf16->f32 map) ----
__device__ __forceinline__ float bf2f(u16 u){ return __uint_as_float(((unsigned)u) << 16); }
__device__ __forceinline__ u16 f2bf(float f){
    __hip_bfloat16 h = __float2bfloat16(f);
    return *reinterpret_cast<u16*>(&h);
}

// ---- DPP add helpers (VALU pipe, no LDS traffic) ----
template<int CTRL, int RM, int BM>
__device__ __forceinline__ float dpp_add(float x){
    int y = __builtin_amdgcn_update_dpp(0, __float_as_int(x), CTRL, RM, BM, false);
    return x + __int_as_float(y);
}
__device__ __forceinline__ float wave_sum63(float x){
    x = dpp_add<0x111,0xf,0xf>(x);
    x = dpp_add<0x112,0xf,0xf>(x);
    x = dpp_add<0x114,0xf,0xe>(x);
    x = dpp_add<0x118,0xf,0xc>(x);
    x = dpp_add<0x142,0xa,0xf>(x);
    x = dpp_add<0x143,0xc,0xf>(x);
    return x;
}
__device__ __forceinline__ float wave_sum_bcast(float x){
    return __int_as_float(__builtin_amdgcn_readlane(__float_as_int(wave_sum63(x)), 63));
}
// 16-lane-row sum via rotate-add: every lane of the row ends with the row total
__device__ __forceinline__ float row_ror_add(float x){
    x = dpp_add<0x121,0xf,0xf>(x);
    x = dpp_add<0x122,0xf,0xf>(x);
    x = dpp_add<0x124,0xf,0xf>(x);
    x = dpp_add<0x128,0xf,0xf>(x);
    return x;
}

// ---- device-scope grid barrier (all CSR_BLOCKS blocks resident by construction) ----
__device__ __forceinline__ void gridbar(int* bar, int slot){
    __syncthreads();
    if (threadIdx.x == 0){
        __threadfence();
        __hip_atomic_fetch_add(&bar[slot], 1, __ATOMIC_ACQ_REL, __HIP_MEMORY_SCOPE_AGENT);
        while (__hip_atomic_load(&bar[slot], __ATOMIC_ACQUIRE, __HIP_MEMORY_SCOPE_AGENT) < CSR_BLOCKS) {}
    }
    __syncthreads();
}

// ---------------- fused CSR build: zero -> count -> scan -> scatter ----------------
__global__ __launch_bounds__(1024) void csr_kernel(
        const int* __restrict__ esrc, const int* __restrict__ edst, int E,
        int* __restrict__ counts, float* __restrict__ muAcc,
        int* __restrict__ indptr, int* __restrict__ cursor, int* __restrict__ col,
        int* __restrict__ bsum, int* __restrict__ boff, int* __restrict__ bar){
    __shared__ int bufA[1024];
    __shared__ int bufB[1024];
    int tid = threadIdx.x, blk = blockIdx.x;
    const int gsz = CSR_BLOCKS * 1024;
    int gid = blk*1024 + tid;
    // phase 0: zero counts + muAcc
    for (int i = gid; i < T_NODES; i += gsz) counts[i] = 0;
    if (gid < BGR*D) muAcc[gid] = 0.f;
    gridbar(bar, 0);
    // phase 1: count
    for (int i = gid; i < E; i += gsz) atomicAdd(&counts[edst[i]], 1);
    gridbar(bar, 1);
    // phase 2: blocks 0..31 scan their 1024 counts
    int myVal = 0, myIncl = 0;
    if (blk < 32){
        myVal = counts[blk*1024 + tid];
        bufA[tid] = myVal;
        __syncthreads();
        int* s = bufA; int* d = bufB;
        for (int off = 1; off < 1024; off <<= 1){
            int v = s[tid];
            if (tid >= off) v += s[tid - off];
            d[tid] = v;
            __syncthreads();
            int* t0 = s; s = d; d = t0;
        }
        myIncl = s[tid];
        if (tid == 1023) bsum[blk] = myIncl;
    }
    gridbar(bar, 2);
    // phase 3: block 0 scans the 32 block sums (shfl_up wave scan)
    if (blk == 0 && tid < 32){
        int v = bsum[tid];
        int inc = v;
        #pragma unroll
        for (int o = 1; o < 32; o <<= 1){
            int y = __shfl_up(inc, o, 64);
            if (tid >= o) inc += y;
        }
        boff[tid] = inc - v;                     // exclusive offset
    }
    gridbar(bar, 3);
    // phase 4: write indptr / cursor
    if (blk < 32){
        int off = boff[blk];
        int excl = off + myIncl - myVal;
        indptr[blk*1024 + tid] = excl;
        cursor[blk*1024 + tid] = excl;
        if (blk == 31 && tid == 1023) indptr[T_NODES] = off + myIncl;
    }
    gridbar(bar, 4);
    // phase 5: scatter
    for (int i = gid; i < E; i += gsz){
        int d0 = edst[i];
        int pos = atomicAdd(&cursor[d0], 1);
        col[pos] = esrc[i];
    }
}

// ---------------- layer 0 linear: bf16 xl/xr out ----------------
__global__ void lin0_kernel(const float* __restrict__ x, const float* __restrict__ Wl0,
                            const float* __restrict__ Wr0,
                            u16* __restrict__ xlb, u16* __restrict__ xrb){
    __shared__ float wl[D][FIN+1];
    __shared__ float wr[D][FIN+1];
    __shared__ float xs[32][FIN];
    int tid = threadIdx.x;
    int blk = blockIdx.x;
    int rowBase = (blk & 7)*4096 + (blk >> 3)*32;     // XCD swizzle
    for (int i = tid; i < D*FIN; i += 256){
        wl[i>>3][i&7] = Wl0[i];
        wr[i>>3][i&7] = Wr0[i];
    }
    xs[tid>>3][tid&7] = x[rowBase*FIN + tid];
    __syncthreads();
    int wave = tid >> 6, lane = tid & 63;
    int rb = rowBase + wave*8;
    #pragma unroll
    for (int r = 0; r < 8; r++){
        float al = 0.f, ar = 0.f;
        int lr = wave*8 + r;
        #pragma unroll
        for (int k = 0; k < FIN; k++){
            float xv = xs[lr][k];
            al = fmaf(xv, wl[lane][k], al);
            ar = fmaf(xv, wr[lane][k], ar);
        }
        xlb[(size_t)(rb+r)*D + lane] = f2bf(al);
        xrb[(size_t)(rb+r)*D + lane] = f2bf(ar);
    }
}

// ---------------- fused edge(layer i) + lin(layer i) ----------------
// 64 nodes/block. Edge phase: 4 waves x 16 nodes, bf16 gathers, row-DPP softmax,
// relu(h) -> LDS. Lin phase: 64x64 LDS tile GEMM -> bf16 xl/xr (ping-pong out).
__global__ __launch_bounds__(256) void el_kernel(
        const u16* __restrict__ xlin, const u16* __restrict__ xrin,
        const float* __restrict__ att, const float* __restrict__ bias,
        const int* __restrict__ indptr, const int* __restrict__ col,
        const float* __restrict__ Wl, const float* __restrict__ Wr,
        u16* __restrict__ xlout, u16* __restrict__ xrout, int E){
    __shared__ __align__(16) float hs[D][68];
    __shared__ __align__(16) float wls[D][68];
    __shared__ __align__(16) float wrs[D][68];
    int tid = threadIdx.x, blk = blockIdx.x;
    int rowBase = (blk & 7)*4096 + (blk >> 3)*64;     // XCD swizzle
    for (int i = tid; i < D*D; i += 256){             // stage next-layer weights
        wls[i>>6][i&63] = Wl[i];
        wrs[i>>6][i&63] = Wr[i];
    }
    int wave = tid >> 6, lane = tid & 63;
    int row = lane >> 4, sub4 = (lane & 15) << 2;
    float4 a4 = *(const float4*)&att[sub4];
    float4 b4 = *(const float4*)&bias[sub4];
    for (int n = 0; n < 16; n++){
        int ln = wave*16 + n;
        int t  = rowBase + ln;
        ushort4 ur = *(const ushort4*)&xrin[((size_t)t << 6) + sub4];
        float4 xr4 = make_float4(bf2f(ur.x), bf2f(ur.y), bf2f(ur.z), bf2f(ur.w));
        int beg = indptr[t], end = indptr[t+1];
        int deg = end - beg;
        int idx = beg + lane; idx = idx < E ? idx : E - 1;
        int sAll = (lane < deg) ? col[idx] : t;       // lanes >= deg: self-loop src
        int nEdge = deg + 1;
        float4 acc = make_float4(0.f,0.f,0.f,0.f);
        float l = 0.f;
        if (nEdge <= 32){
            ushort4 u[8];
            #pragma unroll
            for (int i = 0; i < 8; i++){              // burst: 8 loads in flight
                int j = i*4 + row;
                int jc = (j < nEdge) ? j : (nEdge-1);
                int s = __shfl(sAll, jc, 64);
                u[i] = *(const ushort4*)&xlin[((size_t)(unsigned)s << 6) + sub4];
            }
            #pragma unroll
            for (int i = 0; i < 8; i++){
                float4 xv = make_float4(bf2f(u[i].x), bf2f(u[i].y), bf2f(u[i].z), bf2f(u[i].w));
                float v, e;
                v = xv.x + xr4.x; v = fmaxf(v, 0.2f*v); e = v*a4.x;
                v = xv.y + xr4.y; v = fmaxf(v, 0.2f*v); e = fmaf(v, a4.y, e);
                v = xv.z + xr4.z; v = fmaxf(v, 0.2f*v); e = fmaf(v, a4.z, e);
                v = xv.w + xr4.w; v = fmaxf(v, 0.2f*v); e = fmaf(v, a4.w, e);
                e = row_ror_add(e);
                float q = (i*4 + row < nEdge) ? __expf(e) : 0.f;
                l += q;
                acc.x = fmaf(q, xv.x, acc.x);
                acc.y = fmaf(q, xv.y, acc.y);
                acc.z = fmaf(q, xv.z, acc.z);
                acc.w = fmaf(q, xv.w, acc.w);
            }
        } else {
            for (int j0 = 0; j0 < nEdge; j0 += 4){
                int j = j0 + row;
                int jc = (j < nEdge) ? j : (nEdge-1);
                int s;
                if (jc < 64) s = __shfl(sAll, jc, 64);
                else         s = (jc < deg) ? col[beg + jc] : t;
                ushort4 uu = *(const ushort4*)&xlin[((size_t)(unsigned)s << 6) + sub4];
                float4 xv = make_float4(bf2f(uu.x), bf2f(uu.y), bf2f(uu.z), bf2f(uu.w));
                float v, e;
                v = xv.x + xr4.x; v = fmaxf(v, 0.2f*v); e = v*a4.x;
                v = xv.y + xr4.y; v = fmaxf(v, 0.2f*v); e = fmaf(v, a4.y, e);
                v = xv.z + xr4.z; v = fmaxf(v, 0.2f*v); e = fmaf(v, a4.z, e);
                v = xv.w + xr4.w; v = fmaxf(v, 0.2f*v); e = fmaf(v, a4.w, e);
                e = row_ror_add(e);
                float q = (j < nEdge) ? __expf(e) : 0.f;
                l += q;
                acc.x = fmaf(q, xv.x, acc.x);
                acc.y = fmaf(q, xv.y, acc.y);
                acc.z = fmaf(q, xv.z, acc.z);
                acc.w = fmaf(q, xv.w, acc.w);
            }
        }
        #pragma unroll
        for (int o = 16; o < 64; o <<= 1){
            acc.x += __shfl_xor(acc.x, o, 64);
            acc.y += __shfl_xor(acc.y, o, 64);
            acc.z += __shfl_xor(acc.z, o, 64);
            acc.w += __shfl_xor(acc.w, o, 64);
            l     += __shfl_xor(l,     o, 64);
        }
        if (row == 0){
            float4 hv;
            hv.x = fmaxf(acc.x / l + b4.x, 0.f);      // relu here (input to lin)
            hv.y = fmaxf(acc.y / l + b4.y, 0.f);
            hv.z = fmaxf(acc.z / l + b4.z, 0.f);
            hv.w = fmaxf(acc.w / l + b4.w, 0.f);
            *(float4*)&hs[ln][sub4] = hv;
        }
    }
    __syncthreads();
    // ---- lin phase: xl/xr = hs @ W.T (hs already relu'd) ----
    int ty = tid >> 4, tx = tid & 15;
    int r0 = ty * 4;
    float accl[4][4], accr[4][4];
    #pragma unroll
    for (int i = 0; i < 4; i++)
        #pragma unroll
        for (int j = 0; j < 4; j++){ accl[i][j] = 0.f; accr[i][j] = 0.f; }
    for (int k = 0; k < D; k += 4){
        float4 hv[4], wlv[4], wrv[4];
        #pragma unroll
        for (int i = 0; i < 4; i++){
            hv[i]  = *(const float4*)&hs[r0+i][k];
            wlv[i] = *(const float4*)&wls[tx + 16*i][k];
            wrv[i] = *(const float4*)&wrs[tx + 16*i][k];
        }
        #pragma unroll
        for (int i = 0; i < 4; i++){
            #pragma unroll
            for (int j = 0; j < 4; j++){
                accl[i][j] += hv[i].x*wlv[j].x + hv[i].y*wlv[j].y
                            + hv[i].z*wlv[j].z + hv[i].w*wlv[j].w;
                accr[i][j] += hv[i].x*wrv[j].x + hv[i].y*wrv[j].y
                            + hv[i].z*wrv[j].z + hv[i].w*wrv[j].w;
            }
        }
    }
    #pragma unroll
    for (int i = 0; i < 4; i++){
        size_t rowOff = (size_t)(rowBase + r0 + i) * D;
        #pragma unroll
        for (int j = 0; j < 4; j++){
            xlout[rowOff + tx + 16*j] = f2bf(accl[i][j]);
            xrout[rowOff + tx + 16*j] = f2bf(accr[i][j]);
        }
    }
}

// ---------------- last edge layer: bf16 in, fp32 h out + graph-mean ----------------
__global__ __launch_bounds__(256) void e4_kernel(
        const u16* __restrict__ xlin, const u16* __restrict__ xrin,
        const float* __restrict__ att, const float* __restrict__ bias,
        const int* __restrict__ indptr, const int* __restrict__ col,
        float* __restrict__ hout, float* __restrict__ muAcc, int E){
    int wave = threadIdx.x >> 6, lane = threadIdx.x & 63;
    int blk = blockIdx.x;
    int t = (blk & 7)*4096 + (blk >> 3)*4 + wave;
    int row = lane >> 4, sub4 = (lane & 15) << 2;
    float4 a4 = *(const float4*)&att[sub4];
    ushort4 ur = *(const ushort4*)&xrin[((size_t)t << 6) + sub4];
    float4 xr4 = make_float4(bf2f(ur.x), bf2f(ur.y), bf2f(ur.z), bf2f(ur.w));
    int beg = indptr[t], end = indptr[t+1];
    int deg = end - beg;
    int idx = beg + lane; idx = idx < E ? idx : E - 1;
    int sAll = (lane < deg) ? col[idx] : t;
    int nEdge = deg + 1;
    float4 acc = make_float4(0.f,0.f,0.f,0.f);
    float l = 0.f;
    if (nEdge <= 32){
        ushort4 u[8];
        #pragma unroll
        for (int i = 0; i < 8; i++){
            int j = i*4 + row;
            int jc = (j < nEdge) ? j : (nEdge-1);
            int s = __shfl(sAll, jc, 64);
            u[i] = *(const ushort4*)&xlin[((size_t)(unsigned)s << 6) + sub4];
        }
        #pragma unroll
        for (int i = 0; i < 8; i++){
            float4 xv = make_float4(bf2f(u[i].x), bf2f(u[i].y), bf2f(u[i].z), bf2f(u[i].w));
            float v, e;
            v = xv.x + xr4.x; v = fmaxf(v, 0.2f*v); e = v*a4.x;
            v = xv.y + xr4.y; v = fmaxf(v, 0.2f*v); e = fmaf(v, a4.y, e);
            v = xv.z + xr4.z; v = fmaxf(v, 0.2f*v); e = fmaf(v, a4.z, e);
            v = xv.w + xr4.w; v = fmaxf(v, 0.2f*v); e = fmaf(v, a4.w, e);
            e = row_ror_add(e);
            float q = (i*4 + row < nEdge) ? __expf(e) : 0.f;
            l += q;
            acc.x = fmaf(q, xv.x, acc.x);
            acc.y = fmaf(q, xv.y, acc.y);
            acc.z = fmaf(q, xv.z, acc.z);
            acc.w = fmaf(q, xv.w, acc.w);
        }
    } else {
        for (int j0 = 0; j0 < nEdge; j0 += 4){
            int j = j0 + row;
            int jc = (j < nEdge) ? j : (nEdge-1);
            int s;
            if (jc < 64) s = __shfl(sAll, jc, 64);
            else         s = (jc < deg) ? col[beg + jc] : t;
            ushort4 uu = *(const ushort4*)&xlin[((size_t)(unsigned)s << 6) + sub4];
            float4 xv = make_float4(bf2f(uu.x), bf2f(uu.y), bf2f(uu.z), bf2f(uu.w));
            float v, e;
            v = xv.x + xr4.x; v = fmaxf(v, 0.2f*v); e = v*a4.x;
            v = xv.y + xr4.y; v = fmaxf(v, 0.2f*v); e = fmaf(v, a4.y, e);
            v = xv.z + xr4.z; v = fmaxf(v, 0.2f*v); e = fmaf(v, a4.z, e);
            v = xv.w + xr4.w; v = fmaxf(v, 0.2f*v); e = fmaf(v, a4.w, e);
            e = row_ror_add(e);
            float q = (j < nEdge) ? __expf(e) : 0.f;
            l += q;
            acc.x = fmaf(q, xv.x, acc.x);
            acc.y = fmaf(q, xv.y, acc.y);
            acc.z = fmaf(q, xv.z, acc.z);
            acc.w = fmaf(q, xv.w, acc.w);
        }
    }
    #pragma unroll
    for (int o = 16; o < 64; o <<= 1){
        acc.x += __shfl_xor(acc.x, o, 64);
        acc.y += __shfl_xor(acc.y, o, 64);
        acc.z += __shfl_xor(acc.z, o, 64);
        acc.w += __shfl_xor(acc.w, o, 64);
        l     += __shfl_xor(l,     o, 64);
    }
    float4 b4 = *(const float4*)&bias[sub4];
    float4 hv;
    hv.x = acc.x / l + b4.x;                          // NO relu (final h)
    hv.y = acc.y / l + b4.y;
    hv.z = acc.z / l + b4.z;
    hv.w = acc.w / l + b4.w;
    if (row == 0)
        *(float4*)&hout[(size_t)t*D + sub4] = hv;
    __shared__ float red[4][D];
    if (row == 0) *(float4*)&red[wave][sub4] = hv;
    __syncthreads();
    if (wave == 0){
        float s = red[0][lane] + red[1][lane] + red[2][lane] + red[3][lane];
        atomicAdd(&muAcc[(t >> 10)*D + lane], s);
    }
}

// ---------------- per-node head with inlined per-graph pool ----------------
__global__ __launch_bounds__(256) void final_kernel(const float* __restrict__ h,
                             const float* __restrict__ muAcc,
                             const float* __restrict__ t6w, const float* __restrict__ t6b,
                             const float* __restrict__ t7w, const float* __restrict__ t7b,
                             const float* __restrict__ t5pw, const float* __restrict__ t5pb,
                             const float* __restrict__ t5vw, const float* __restrict__ t5vb,
                             const float* __restrict__ pw, const float* __restrict__ pb,
                             const int* __restrict__ reachable,
                             float* __restrict__ out_logits, float* __restrict__ qbuf){
    __shared__ __align__(16) float hs[D][68];
    __shared__ __align__(16) float ws[D][68];
    __shared__ float ppar[D][17];
    __shared__ float qpar[D][17];
    __shared__ float PgQg[2];
    int tid = threadIdx.x;
    int blk = blockIdx.x;
    int rowBase = (blk & 7)*4096 + (blk >> 3)*64;
    int b = rowBase >> 10;
    for (int i = tid; i < D*D; i += 256) ws[i>>6][i&63] = t6w[i];
    if (tid < D) hs[0][tid] = muAcc[b*D + tid] * (1.f/NPG);
    __syncthreads();
    if (tid < D){
        int d = tid;
        float g = t6b[d];
        #pragma unroll
        for (int k = 0; k < D; k++) g = fmaf(hs[0][k], ws[d][k], g);
        g = fmaxf(g, 0.f);
        float pp = wave_sum_bcast(g * t5pw[d]);
        float qq = wave_sum_bcast(g * t5vw[d]);
        if (d == 0){ PgQg[0] = pp; PgQg[1] = qq; }
    }
    __syncthreads();
    for (int i = tid; i < D*D; i += 256){
        int r = i >> 6, c = i & 63;
        hs[r][c] = h[(size_t)rowBase*D + i];
        ws[r][c] = t7w[i];
    }
    __syncthreads();
    int ty = tid >> 4, tx = tid & 15;
    int r0 = ty * 4;
    float acc[4][4];
    #pragma unroll
    for (int i = 0; i < 4; i++)
        #pragma unroll
        for (int j = 0; j < 4; j++) acc[i][j] = 0.f;
    for (int k = 0; k < D; k += 4){
        float4 hv[4], wv[4];
        #pragma unroll
        for (int i = 0; i < 4; i++){
            hv[i] = *(const float4*)&hs[r0+i][k];
            wv[i] = *(const float4*)&ws[tx + 16*i][k];
        }
        #pragma unroll
        for (int i = 0; i < 4; i++)
            #pragma unroll
            for (int j = 0; j < 4; j++)
                acc[i][j] += hv[i].x*wv[j].x + hv[i].y*wv[j].y
                           + hv[i].z*wv[j].z + hv[i].w*wv[j].w;
    }
    float bc[4], pwc[4], qwc[4];
    #pragma unroll
    for (int j = 0; j < 4; j++){
        int c = tx + 16*j;
        bc[j]  = t7b[c];
        pwc[j] = t5pw[D + c];
        qwc[j] = t5vw[D + c];
    }
    #pragma unroll
    for (int i = 0; i < 4; i++){
        float sp = 0.f, sq = 0.f;
        #pragma unroll
        for (int j = 0; j < 4; j++){
            float lv = fmaxf(acc[i][j] + bc[j], 0.f);
            sp = fmaf(lv, pwc[j], sp);
            sq = fmaf(lv, qwc[j], sq);
        }
        ppar[r0+i][tx] = sp;
        qpar[r0+i][tx] = sq;
    }
    __syncthreads();
    if (tid < 64){
        int t = rowBase + tid;
        float sp = 0.f, sq = 0.f;
        #pragma unroll
        for (int c = 0; c < 16; c++){ sp += ppar[tid][c]; sq += qpar[tid][c]; }
        float prob = PgQg[0] + sp + t5pb[0];
        out_logits[t] = prob * pw[0] + pb[0];
        float q = PgQg[1] + sq + t5vb[0];
        if (!reachable[t]) q = -1e20f;
        qbuf[t] = q;
    }
}

// ---------------- per-graph masked max -> value ----------------
__global__ void value_kernel(const float* __restrict__ qbuf, const float* __restrict__ vw,
                             const float* __restrict__ vb, float* __restrict__ out_value){
    __shared__ float part[256];
    int b = blockIdx.x, tid = threadIdx.x;
    float m = -INFINITY;
    for (int i = tid; i < NPG; i += 256) m = fmaxf(m, qbuf[b*NPG + i]);
    part[tid] = m;
    __syncthreads();
    for (int s = 128; s > 0; s >>= 1){
        if (tid < s) part[tid] = fmaxf(part[tid], part[tid+s]);
        __syncthreads();
    }
    if (tid == 0) out_value[b] = part[0]*vw[0] + vb[0];
}

extern "C" void kernel_launch(void* const* d_in, const int* in_sizes, int n_in,
                              void* d_out, int out_size, void* d_ws, size_t ws_size,
                              hipStream_t stream){
    const float* x          = (const float*)d_in[0];
    const int*   edge_index = (const int*)d_in[1];
    const int*   reachable  = (const int*)d_in[2];
    const float* Wl0 = (const float*)d_in[3];
    const float* Wr0 = (const float*)d_in[4];
    const float* att0= (const float*)d_in[5];
    const float* b0  = (const float*)d_in[6];
    const float* Wl  = (const float*)d_in[7];
    const float* Wr  = (const float*)d_in[8];
    const float* att = (const float*)d_in[9];
    const float* bb  = (const float*)d_in[10];
    const float* t6w = (const float*)d_in[11];
    const float* t6b = (const float*)d_in[12];
    const float* t7w = (const float*)d_in[13];
    const float* t7b = (const float*)d_in[14];
    const float* t5pw= (const float*)d_in[15];
    const float* t5pb= (const float*)d_in[16];
    const float* t5vw= (const float*)d_in[17];
    const float* t5vb= (const float*)d_in[18];
    const float* pw  = (const float*)d_in[19];
    const float* pb  = (const float*)d_in[20];
    const float* vw  = (const float*)d_in[21];
    const float* vb  = (const float*)d_in[22];

    int E = in_sizes[1] / 2;
    const int* esrc = edge_index;
    const int* edst = edge_index + E;

    char* ws = (char*)d_ws;
    float* h    = (float*)(ws);                                   // 8 MB
    u16* xlbA   = (u16*)(ws + (size_t)T_NODES*D*4);               // 4 MB
    u16* xrbA   = (u16*)((char*)xlbA + (size_t)T_NODES*D*2);
    u16* xlbB   = (u16*)((char*)xrbA + (size_t)T_NODES*D*2);
    u16* xrbB   = (u16*)((char*)xlbB + (size_t)T_NODES*D*2);
    int* counts = (int*)((char*)xrbB + (size_t)T_NODES*D*2);
    int* indptr = (int*)((char*)counts + (size_t)(T_NODES+16)*4);
    int* cursor = (int*)((char*)indptr + (size_t)(T_NODES+16)*4);
    int* col    = (int*)((char*)cursor + (size_t)(T_NODES+16)*4);
    float* qbuf = (float*)((char*)col + (size_t)(E+64)*4);
    float* muAcc= (float*)((char*)qbuf + (size_t)T_NODES*4);
    int* bsum   = (int*)((char*)muAcc + (size_t)BGR*D*4);
    int* boff   = bsum + 64;
    int* bar    = boff + 64;

    hipMemsetAsync(bar, 0, 64, stream);
    csr_kernel<<<CSR_BLOCKS, 1024, 0, stream>>>(esrc, edst, E, counts, muAcc,
                                                indptr, cursor, col, bsum, boff, bar);
    lin0_kernel<<<T_NODES/32, 256, 0, stream>>>(x, Wl0, Wr0, xlbA, xrbA);

    // EL_i: edge of layer i (+relu) then lin with Wl[i]/Wr[i]; ping-pong A/B
    el_kernel<<<T_NODES/64, 256, 0, stream>>>(xlbA, xrbA, att0, b0, indptr, col,
                                              Wl + 0*D*D, Wr + 0*D*D, xlbB, xrbB, E);
    el_kernel<<<T_NODES/64, 256, 0, stream>>>(xlbB, xrbB, att + 0*D, bb + 0*D, indptr, col,
                                              Wl + 1*D*D, Wr + 1*D*D, xlbA, xrbA, E);
    el_kernel<<<T_NODES/64, 256, 0, stream>>>(xlbA, xrbA, att + 1*D, bb + 1*D, indptr, col,
                                              Wl + 2*D*D, Wr + 2*D*D, xlbB, xrbB, E);
    el_kernel<<<T_NODES/64, 256, 0, stream>>>(xlbB, xrbB, att + 2*D, bb + 2*D, indptr, col,
                                              Wl + 3*D*D, Wr + 3*D*D, xlbA, xrbA, E);
    e4_kernel<<<T_NODES/4, 256, 0, stream>>>(xlbA, xrbA, att + 3*D, bb + 3*D, indptr, col,
                                             h, muAcc, E);

    final_kernel<<<T_NODES/64, 256, 0, stream>>>(h, muAcc, t6w, t6b, t7w, t7b,
                                                 t5pw, t5pb, t5vw, t5vb, pw, pb,
                                                 reachable, (float*)d_out, qbuf);
    value_kernel<<<BGR, 256, 0, stream>>>(qbuf, vw, vb, (float*)d_out + T_NODES);
}

// Round 10
// 328.995 us; speedup vs baseline: 1.1067x; 1.1067x over previous
//
#include <hip/hip_runtime.h>
#include <hip/hip_bf16.h>

typedef unsigned short u16;

#define T_NODES 32768
#define NPG 1024
#define BGR 32
#define D 64
#define FIN 8

// ---- bf16 <-> f32 ----
__device__ __forceinline__ float bf2f(u16 u){ return __uint_as_float(((unsigned)u) << 16); }
__device__ __forceinline__ u16 f2bf(float f){
    __hip_bfloat16 h = __float2bfloat16(f);
    return *reinterpret_cast<u16*>(&h);
}

// ---- DPP add helpers (VALU pipe, no LDS traffic) ----
template<int CTRL, int RM, int BM>
__device__ __forceinline__ float dpp_add(float x){
    int y = __builtin_amdgcn_update_dpp(0, __float_as_int(x), CTRL, RM, BM, false);
    return x + __int_as_float(y);
}
__device__ __forceinline__ float wave_sum63(float x){
    x = dpp_add<0x111,0xf,0xf>(x);
    x = dpp_add<0x112,0xf,0xf>(x);
    x = dpp_add<0x114,0xf,0xe>(x);
    x = dpp_add<0x118,0xf,0xc>(x);
    x = dpp_add<0x142,0xa,0xf>(x);
    x = dpp_add<0x143,0xc,0xf>(x);
    return x;
}
__device__ __forceinline__ float wave_sum_bcast(float x){
    return __int_as_float(__builtin_amdgcn_readlane(__float_as_int(wave_sum63(x)), 63));
}
// 16-lane-row sum via rotate-add: every lane of the row ends with the row total
__device__ __forceinline__ float row_ror_add(float x){
    x = dpp_add<0x121,0xf,0xf>(x);
    x = dpp_add<0x122,0xf,0xf>(x);
    x = dpp_add<0x124,0xf,0xf>(x);
    x = dpp_add<0x128,0xf,0xf>(x);
    return x;
}

// ---- degree-tiered edge accumulation (NIT*4 edge slots, burst loads) ----
template<int NIT>
__device__ __forceinline__ void edge_fast(const u16* __restrict__ xlin,
        int sAll, int nEdge, int row, int sub4,
        float4 a4, float4 xr4, float4& acc, float& l){
    ushort4 u[NIT];
    #pragma unroll
    for (int i = 0; i < NIT; i++){
        int j = i*4 + row;
        int jc = (j < nEdge) ? j : (nEdge-1);
        int s = __shfl(sAll, jc, 64);
        u[i] = *(const ushort4*)&xlin[((size_t)(unsigned)s << 6) + sub4];
    }
    #pragma unroll
    for (int i = 0; i < NIT; i++){
        float4 xv = make_float4(bf2f(u[i].x), bf2f(u[i].y), bf2f(u[i].z), bf2f(u[i].w));
        float v, e;
        v = xv.x + xr4.x; v = fmaxf(v, 0.2f*v); e = v*a4.x;
        v = xv.y + xr4.y; v = fmaxf(v, 0.2f*v); e = fmaf(v, a4.y, e);
        v = xv.z + xr4.z; v = fmaxf(v, 0.2f*v); e = fmaf(v, a4.z, e);
        v = xv.w + xr4.w; v = fmaxf(v, 0.2f*v); e = fmaf(v, a4.w, e);
        e = row_ror_add(e);
        float q = (i*4 + row < nEdge) ? __expf(e) : 0.f;
        l += q;
        acc.x = fmaf(q, xv.x, acc.x);
        acc.y = fmaf(q, xv.y, acc.y);
        acc.z = fmaf(q, xv.z, acc.z);
        acc.w = fmaf(q, xv.w, acc.w);
    }
}

__device__ __forceinline__ void edge_slow(const u16* __restrict__ xlin,
        const int* __restrict__ col, int beg, int deg, int t,
        int sAll, int nEdge, int row, int sub4,
        float4 a4, float4 xr4, float4& acc, float& l){
    for (int j0 = 0; j0 < nEdge; j0 += 4){
        int j = j0 + row;
        int jc = (j < nEdge) ? j : (nEdge-1);
        int s;
        if (jc < 64) s = __shfl(sAll, jc, 64);
        else         s = (jc < deg) ? col[beg + jc] : t;
        ushort4 uu = *(const ushort4*)&xlin[((size_t)(unsigned)s << 6) + sub4];
        float4 xv = make_float4(bf2f(uu.x), bf2f(uu.y), bf2f(uu.z), bf2f(uu.w));
        float v, e;
        v = xv.x + xr4.x; v = fmaxf(v, 0.2f*v); e = v*a4.x;
        v = xv.y + xr4.y; v = fmaxf(v, 0.2f*v); e = fmaf(v, a4.y, e);
        v = xv.z + xr4.z; v = fmaxf(v, 0.2f*v); e = fmaf(v, a4.z, e);
        v = xv.w + xr4.w; v = fmaxf(v, 0.2f*v); e = fmaf(v, a4.w, e);
        e = row_ror_add(e);
        float q = (j < nEdge) ? __expf(e) : 0.f;
        l += q;
        acc.x = fmaf(q, xv.x, acc.x);
        acc.y = fmaf(q, xv.y, acc.y);
        acc.z = fmaf(q, xv.z, acc.z);
        acc.w = fmaf(q, xv.w, acc.w);
    }
}

// ---------------- CSR build (separate kernels: dispatch gaps < spin barriers) ----
__global__ void count_kernel(const int* __restrict__ dst, int* __restrict__ counts, int E){
    int i = blockIdx.x*blockDim.x + threadIdx.x;
    if (i < E) atomicAdd(&counts[dst[i]], 1);
}

__global__ void scan_kernel(const int* __restrict__ counts, int* __restrict__ indptr,
                            int* __restrict__ cursor, int T){
    __shared__ int bufA[1024];
    __shared__ int bufB[1024];
    int tid = threadIdx.x;
    int base = tid * 32;
    int local[32];
    int s = 0;
    #pragma unroll
    for (int i = 0; i < 32; i++){ local[i] = counts[base+i]; s += local[i]; }
    bufA[tid] = s;
    __syncthreads();
    int* src = bufA; int* dst = bufB;
    for (int off = 1; off < 1024; off <<= 1){
        int v = src[tid];
        if (tid >= off) v += src[tid - off];
        dst[tid] = v;
        __syncthreads();
        int* t = src; src = dst; dst = t;
    }
    int excl = src[tid] - s;
    int run = excl;
    #pragma unroll
    for (int i = 0; i < 32; i++){
        indptr[base+i] = run;
        cursor[base+i] = run;
        run += local[i];
    }
    if (tid == 1023) indptr[T] = run;
}

__global__ void scatter_kernel(const int* __restrict__ src, const int* __restrict__ dst,
                               int* __restrict__ cursor, int* __restrict__ col, int E){
    int i = blockIdx.x*blockDim.x + threadIdx.x;
    if (i < E){
        int d = dst[i];
        int pos = atomicAdd(&cursor[d], 1);
        col[pos] = src[i];
    }
}

// ---------------- layer 0 linear + zero-init fused: bf16 xl/xr out ----------------
__global__ void lin0_kernel(const float* __restrict__ x, const float* __restrict__ Wl0,
                            const float* __restrict__ Wr0,
                            u16* __restrict__ xlb, u16* __restrict__ xrb,
                            int* __restrict__ counts, float* __restrict__ muAcc){
    __shared__ float wl[D][FIN+1];
    __shared__ float wr[D][FIN+1];
    __shared__ float xs[32][FIN];
    int tid = threadIdx.x;
    int blk = blockIdx.x;
    int gidx = blk*256 + tid;
    if (gidx < T_NODES) counts[gidx] = 0;             // fused zero
    if (gidx < BGR*D)   muAcc[gidx] = 0.f;
    int rowBase = (blk & 7)*4096 + (blk >> 3)*32;     // XCD swizzle
    for (int i = tid; i < D*FIN; i += 256){
        wl[i>>3][i&7] = Wl0[i];
        wr[i>>3][i&7] = Wr0[i];
    }
    xs[tid>>3][tid&7] = x[rowBase*FIN + tid];
    __syncthreads();
    int wave = tid >> 6, lane = tid & 63;
    int rb = rowBase + wave*8;
    #pragma unroll
    for (int r = 0; r < 8; r++){
        float al = 0.f, ar = 0.f;
        int lr = wave*8 + r;
        #pragma unroll
        for (int k = 0; k < FIN; k++){
            float xv = xs[lr][k];
            al = fmaf(xv, wl[lane][k], al);
            ar = fmaf(xv, wr[lane][k], ar);
        }
        xlb[(size_t)(rb+r)*D + lane] = f2bf(al);
        xrb[(size_t)(rb+r)*D + lane] = f2bf(ar);
    }
}

// ---------------- fused edge(layer i) + lin(layer i) ----------------
__global__ __launch_bounds__(256) void el_kernel(
        const u16* __restrict__ xlin, const u16* __restrict__ xrin,
        const float* __restrict__ att, const float* __restrict__ bias,
        const int* __restrict__ indptr, const int* __restrict__ col,
        const float* __restrict__ Wl, const float* __restrict__ Wr,
        u16* __restrict__ xlout, u16* __restrict__ xrout, int E){
    __shared__ __align__(16) float hs[D][68];
    __shared__ __align__(16) float wls[D][68];
    __shared__ __align__(16) float wrs[D][68];
    int tid = threadIdx.x, blk = blockIdx.x;
    int rowBase = (blk & 7)*4096 + (blk >> 3)*64;     // XCD swizzle
    for (int i = tid; i < D*D; i += 256){
        wls[i>>6][i&63] = Wl[i];
        wrs[i>>6][i&63] = Wr[i];
    }
    int wave = tid >> 6, lane = tid & 63;
    int row = lane >> 4, sub4 = (lane & 15) << 2;
    float4 a4 = *(const float4*)&att[sub4];
    float4 b4 = *(const float4*)&bias[sub4];
    for (int n = 0; n < 16; n++){
        int ln = wave*16 + n;
        int t  = rowBase + ln;
        ushort4 ur = *(const ushort4*)&xrin[((size_t)t << 6) + sub4];
        float4 xr4 = make_float4(bf2f(ur.x), bf2f(ur.y), bf2f(ur.z), bf2f(ur.w));
        int beg = indptr[t], end = indptr[t+1];
        int deg = end - beg;
        int idx = beg + lane; idx = idx < E ? idx : E - 1;
        int sAll = (lane < deg) ? col[idx] : t;
        int nEdge = deg + 1;
        float4 acc = make_float4(0.f,0.f,0.f,0.f);
        float l = 0.f;
        if      (nEdge <= 16) edge_fast<4>(xlin, sAll, nEdge, row, sub4, a4, xr4, acc, l);
        else if (nEdge <= 24) edge_fast<6>(xlin, sAll, nEdge, row, sub4, a4, xr4, acc, l);
        else if (nEdge <= 32) edge_fast<8>(xlin, sAll, nEdge, row, sub4, a4, xr4, acc, l);
        else edge_slow(xlin, col, beg, deg, t, sAll, nEdge, row, sub4, a4, xr4, acc, l);
        #pragma unroll
        for (int o = 16; o < 64; o <<= 1){
            acc.x += __shfl_xor(acc.x, o, 64);
            acc.y += __shfl_xor(acc.y, o, 64);
            acc.z += __shfl_xor(acc.z, o, 64);
            acc.w += __shfl_xor(acc.w, o, 64);
            l     += __shfl_xor(l,     o, 64);
        }
        if (row == 0){
            float4 hv;
            hv.x = fmaxf(acc.x / l + b4.x, 0.f);      // relu (input to lin)
            hv.y = fmaxf(acc.y / l + b4.y, 0.f);
            hv.z = fmaxf(acc.z / l + b4.z, 0.f);
            hv.w = fmaxf(acc.w / l + b4.w, 0.f);
            *(float4*)&hs[ln][sub4] = hv;
        }
    }
    __syncthreads();
    // ---- lin phase: xl/xr = hs @ W.T ----
    int ty = tid >> 4, tx = tid & 15;
    int r0 = ty * 4;
    float accl[4][4], accr[4][4];
    #pragma unroll
    for (int i = 0; i < 4; i++)
        #pragma unroll
        for (int j = 0; j < 4; j++){ accl[i][j] = 0.f; accr[i][j] = 0.f; }
    for (int k = 0; k < D; k += 4){
        float4 hv[4], wlv[4], wrv[4];
        #pragma unroll
        for (int i = 0; i < 4; i++){
            hv[i]  = *(const float4*)&hs[r0+i][k];
            wlv[i] = *(const float4*)&wls[tx + 16*i][k];
            wrv[i] = *(const float4*)&wrs[tx + 16*i][k];
        }
        #pragma unroll
        for (int i = 0; i < 4; i++){
            #pragma unroll
            for (int j = 0; j < 4; j++){
                accl[i][j] += hv[i].x*wlv[j].x + hv[i].y*wlv[j].y
                            + hv[i].z*wlv[j].z + hv[i].w*wlv[j].w;
                accr[i][j] += hv[i].x*wrv[j].x + hv[i].y*wrv[j].y
                            + hv[i].z*wrv[j].z + hv[i].w*wrv[j].w;
            }
        }
    }
    #pragma unroll
    for (int i = 0; i < 4; i++){
        size_t rowOff = (size_t)(rowBase + r0 + i) * D;
        #pragma unroll
        for (int j = 0; j < 4; j++){
            xlout[rowOff + tx + 16*j] = f2bf(accl[i][j]);
            xrout[rowOff + tx + 16*j] = f2bf(accr[i][j]);
        }
    }
}

// ---------------- last edge layer: bf16 in, fp32 h out + graph-mean ----------------
__global__ __launch_bounds__(256) void e4_kernel(
        const u16* __restrict__ xlin, const u16* __restrict__ xrin,
        const float* __restrict__ att, const float* __restrict__ bias,
        const int* __restrict__ indptr, const int* __restrict__ col,
        float* __restrict__ hout, float* __restrict__ muAcc, int E){
    int wave = threadIdx.x >> 6, lane = threadIdx.x & 63;
    int blk = blockIdx.x;
    int t = (blk & 7)*4096 + (blk >> 3)*4 + wave;
    int row = lane >> 4, sub4 = (lane & 15) << 2;
    float4 a4 = *(const float4*)&att[sub4];
    ushort4 ur = *(const ushort4*)&xrin[((size_t)t << 6) + sub4];
    float4 xr4 = make_float4(bf2f(ur.x), bf2f(ur.y), bf2f(ur.z), bf2f(ur.w));
    int beg = indptr[t], end = indptr[t+1];
    int deg = end - beg;
    int idx = beg + lane; idx = idx < E ? idx : E - 1;
    int sAll = (lane < deg) ? col[idx] : t;
    int nEdge = deg + 1;
    float4 acc = make_float4(0.f,0.f,0.f,0.f);
    float l = 0.f;
    if      (nEdge <= 16) edge_fast<4>(xlin, sAll, nEdge, row, sub4, a4, xr4, acc, l);
    else if (nEdge <= 24) edge_fast<6>(xlin, sAll, nEdge, row, sub4, a4, xr4, acc, l);
    else if (nEdge <= 32) edge_fast<8>(xlin, sAll, nEdge, row, sub4, a4, xr4, acc, l);
    else edge_slow(xlin, col, beg, deg, t, sAll, nEdge, row, sub4, a4, xr4, acc, l);
    #pragma unroll
    for (int o = 16; o < 64; o <<= 1){
        acc.x += __shfl_xor(acc.x, o, 64);
        acc.y += __shfl_xor(acc.y, o, 64);
        acc.z += __shfl_xor(acc.z, o, 64);
        acc.w += __shfl_xor(acc.w, o, 64);
        l     += __shfl_xor(l,     o, 64);
    }
    float4 b4 = *(const float4*)&bias[sub4];
    float4 hv;
    hv.x = acc.x / l + b4.x;                          // NO relu (final h)
    hv.y = acc.y / l + b4.y;
    hv.z = acc.z / l + b4.z;
    hv.w = acc.w / l + b4.w;
    if (row == 0)
        *(float4*)&hout[(size_t)t*D + sub4] = hv;
    __shared__ float red[4][D];
    if (row == 0) *(float4*)&red[wave][sub4] = hv;
    __syncthreads();
    if (wave == 0){
        float s = red[0][lane] + red[1][lane] + red[2][lane] + red[3][lane];
        atomicAdd(&muAcc[(t >> 10)*D + lane], s);
    }
}

// ---------------- per-node head with inlined per-graph pool ----------------
__global__ __launch_bounds__(256) void final_kernel(const float* __restrict__ h,
                             const float* __restrict__ muAcc,
                             const float* __restrict__ t6w, const float* __restrict__ t6b,
                             const float* __restrict__ t7w, const float* __restrict__ t7b,
                             const float* __restrict__ t5pw, const float* __restrict__ t5pb,
                             const float* __restrict__ t5vw, const float* __restrict__ t5vb,
                             const float* __restrict__ pw, const float* __restrict__ pb,
                             const int* __restrict__ reachable,
                             float* __restrict__ out_logits, float* __restrict__ qbuf){
    __shared__ __align__(16) float hs[D][68];
    __shared__ __align__(16) float ws[D][68];
    __shared__ float ppar[D][17];
    __shared__ float qpar[D][17];
    __shared__ float PgQg[2];
    int tid = threadIdx.x;
    int blk = blockIdx.x;
    int rowBase = (blk & 7)*4096 + (blk >> 3)*64;
    int b = rowBase >> 10;
    for (int i = tid; i < D*D; i += 256) ws[i>>6][i&63] = t6w[i];
    if (tid < D) hs[0][tid] = muAcc[b*D + tid] * (1.f/NPG);
    __syncthreads();
    if (tid < D){
        int d = tid;
        float g = t6b[d];
        #pragma unroll
        for (int k = 0; k < D; k++) g = fmaf(hs[0][k], ws[d][k], g);
        g = fmaxf(g, 0.f);
        float pp = wave_sum_bcast(g * t5pw[d]);
        float qq = wave_sum_bcast(g * t5vw[d]);
        if (d == 0){ PgQg[0] = pp; PgQg[1] = qq; }
    }
    __syncthreads();
    for (int i = tid; i < D*D; i += 256){
        int r = i >> 6, c = i & 63;
        hs[r][c] = h[(size_t)rowBase*D + i];
        ws[r][c] = t7w[i];
    }
    __syncthreads();
    int ty = tid >> 4, tx = tid & 15;
    int r0 = ty * 4;
    float acc[4][4];
    #pragma unroll
    for (int i = 0; i < 4; i++)
        #pragma unroll
        for (int j = 0; j < 4; j++) acc[i][j] = 0.f;
    for (int k = 0; k < D; k += 4){
        float4 hv[4], wv[4];
        #pragma unroll
        for (int i = 0; i < 4; i++){
            hv[i] = *(const float4*)&hs[r0+i][k];
            wv[i] = *(const float4*)&ws[tx + 16*i][k];
        }
        #pragma unroll
        for (int i = 0; i < 4; i++)
            #pragma unroll
            for (int j = 0; j < 4; j++)
                acc[i][j] += hv[i].x*wv[j].x + hv[i].y*wv[j].y
                           + hv[i].z*wv[j].z + hv[i].w*wv[j].w;
    }
    float bc[4], pwc[4], qwc[4];
    #pragma unroll
    for (int j = 0; j < 4; j++){
        int c = tx + 16*j;
        bc[j]  = t7b[c];
        pwc[j] = t5pw[D + c];
        qwc[j] = t5vw[D + c];
    }
    #pragma unroll
    for (int i = 0; i < 4; i++){
        float sp = 0.f, sq = 0.f;
        #pragma unroll
        for (int j = 0; j < 4; j++){
            float lv = fmaxf(acc[i][j] + bc[j], 0.f);
            sp = fmaf(lv, pwc[j], sp);
            sq = fmaf(lv, qwc[j], sq);
        }
        ppar[r0+i][tx] = sp;
        qpar[r0+i][tx] = sq;
    }
    __syncthreads();
    if (tid < 64){
        int t = rowBase + tid;
        float sp = 0.f, sq = 0.f;
        #pragma unroll
        for (int c = 0; c < 16; c++){ sp += ppar[tid][c]; sq += qpar[tid][c]; }
        float prob = PgQg[0] + sp + t5pb[0];
        out_logits[t] = prob * pw[0] + pb[0];
        float q = PgQg[1] + sq + t5vb[0];
        if (!reachable[t]) q = -1e20f;
        qbuf[t] = q;
    }
}

// ---------------- per-graph masked max -> value ----------------
__global__ void value_kernel(const float* __restrict__ qbuf, const float* __restrict__ vw,
                             const float* __restrict__ vb, float* __restrict__ out_value){
    __shared__ float part[256];
    int b = blockIdx.x, tid = threadIdx.x;
    float m = -INFINITY;
    for (int i = tid; i < NPG; i += 256) m = fmaxf(m, qbuf[b*NPG + i]);
    part[tid] = m;
    __syncthreads();
    for (int s = 128; s > 0; s >>= 1){
        if (tid < s) part[tid] = fmaxf(part[tid], part[tid+s]);
        __syncthreads();
    }
    if (tid == 0) out_value[b] = part[0]*vw[0] + vb[0];
}

extern "C" void kernel_launch(void* const* d_in, const int* in_sizes, int n_in,
                              void* d_out, int out_size, void* d_ws, size_t ws_size,
                              hipStream_t stream){
    const float* x          = (const float*)d_in[0];
    const int*   edge_index = (const int*)d_in[1];
    const int*   reachable  = (const int*)d_in[2];
    const float* Wl0 = (const float*)d_in[3];
    const float* Wr0 = (const float*)d_in[4];
    const float* att0= (const float*)d_in[5];
    const float* b0  = (const float*)d_in[6];
    const float* Wl  = (const float*)d_in[7];
    const float* Wr  = (const float*)d_in[8];
    const float* att = (const float*)d_in[9];
    const float* bb  = (const float*)d_in[10];
    const float* t6w = (const float*)d_in[11];
    const float* t6b = (const float*)d_in[12];
    const float* t7w = (const float*)d_in[13];
    const float* t7b = (const float*)d_in[14];
    const float* t5pw= (const float*)d_in[15];
    const float* t5pb= (const float*)d_in[16];
    const float* t5vw= (const float*)d_in[17];
    const float* t5vb= (const float*)d_in[18];
    const float* pw  = (const float*)d_in[19];
    const float* pb  = (const float*)d_in[20];
    const float* vw  = (const float*)d_in[21];
    const float* vb  = (const float*)d_in[22];

    int E = in_sizes[1] / 2;
    const int* esrc = edge_index;
    const int* edst = edge_index + E;

    char* ws = (char*)d_ws;
    float* h    = (float*)(ws);
    u16* xlbA   = (u16*)(ws + (size_t)T_NODES*D*4);
    u16* xrbA   = (u16*)((char*)xlbA + (size_t)T_NODES*D*2);
    u16* xlbB   = (u16*)((char*)xrbA + (size_t)T_NODES*D*2);
    u16* xrbB   = (u16*)((char*)xlbB + (size_t)T_NODES*D*2);
    int* counts = (int*)((char*)xrbB + (size_t)T_NODES*D*2);
    int* indptr = (int*)((char*)counts + (size_t)(T_NODES+16)*4);
    int* cursor = (int*)((char*)indptr + (size_t)(T_NODES+16)*4);
    int* col    = (int*)((char*)cursor + (size_t)(T_NODES+16)*4);
    float* qbuf = (float*)((char*)col + (size_t)(E+64)*4);
    float* muAcc= (float*)((char*)qbuf + (size_t)T_NODES*4);

    // lin0 zero-inits counts + muAcc; count/scan/scatter follow
    lin0_kernel<<<T_NODES/32, 256, 0, stream>>>(x, Wl0, Wr0, xlbA, xrbA, counts, muAcc);
    count_kernel<<<(E+255)/256, 256, 0, stream>>>(edst, counts, E);
    scan_kernel<<<1, 1024, 0, stream>>>(counts, indptr, cursor, T_NODES);
    scatter_kernel<<<(E+255)/256, 256, 0, stream>>>(esrc, edst, cursor, col, E);

    // EL_i: edge of layer i (+relu) then lin with Wl[i]/Wr[i]; ping-pong A/B
    el_kernel<<<T_NODES/64, 256, 0, stream>>>(xlbA, xrbA, att0, b0, indptr, col,
                                              Wl + 0*D*D, Wr + 0*D*D, xlbB, xrbB, E);
    el_kernel<<<T_NODES/64, 256, 0, stream>>>(xlbB, xrbB, att + 0*D, bb + 0*D, indptr, col,
                                              Wl + 1*D*D, Wr + 1*D*D, xlbA, xrbA, E);
    el_kernel<<<T_NODES/64, 256, 0, stream>>>(xlbA, xrbA, att + 1*D, bb + 1*D, indptr, col,
                                              Wl + 2*D*D, Wr + 2*D*D, xlbB, xrbB, E);
    el_kernel<<<T_NODES/64, 256, 0, stream>>>(xlbB, xrbB, att + 2*D, bb + 2*D, indptr, col,
                                              Wl + 3*D*D, Wr + 3*D*D, xlbA, xrbA, E);
    e4_kernel<<<T_NODES/4, 256, 0, stream>>>(xlbA, xrbA, att + 3*D, bb + 3*D, indptr, col,
                                             h, muAcc, E);

    final_kernel<<<T_NODES/64, 256, 0, stream>>>(h, muAcc, t6w, t6b, t7w, t7b,
                                                 t5pw, t5pb, t5vw, t5vb, pw, pb,
                                                 reachable, (float*)d_out, qbuf);
    value_kernel<<<BGR, 256, 0, stream>>>(qbuf, vw, vb, (float*)d_out + T_NODES);
}

// Round 11
// 313.887 us; speedup vs baseline: 1.1599x; 1.0481x over previous
//
#include <hip/hip_runtime.h>
#include <hip/hip_bf16.h>

typedef unsigned short u16;

#define T_NODES 32768
#define NPG 1024
#define BGR 32
#define D 64
#define FIN 8

// ---- bf16 <-> f32 ----
__device__ __forceinline__ float bf2f(u16 u){ return __uint_as_float(((unsigned)u) << 16); }
__device__ __forceinline__ u16 f2bf(float f){
    __hip_bfloat16 h = __float2bfloat16(f);
    return *reinterpret_cast<u16*>(&h);
}
__device__ __forceinline__ float4 bf4(ushort4 u){
    return make_float4(bf2f(u.x), bf2f(u.y), bf2f(u.z), bf2f(u.w));
}

// ---- DPP add helpers (VALU pipe, no LDS traffic) ----
template<int CTRL, int RM, int BM>
__device__ __forceinline__ float dpp_add(float x){
    int y = __builtin_amdgcn_update_dpp(0, __float_as_int(x), CTRL, RM, BM, false);
    return x + __int_as_float(y);
}
__device__ __forceinline__ float wave_sum63(float x){
    x = dpp_add<0x111,0xf,0xf>(x);
    x = dpp_add<0x112,0xf,0xf>(x);
    x = dpp_add<0x114,0xf,0xe>(x);
    x = dpp_add<0x118,0xf,0xc>(x);
    x = dpp_add<0x142,0xa,0xf>(x);
    x = dpp_add<0x143,0xc,0xf>(x);
    return x;
}
__device__ __forceinline__ float wave_sum_bcast(float x){
    return __int_as_float(__builtin_amdgcn_readlane(__float_as_int(wave_sum63(x)), 63));
}
// 16-lane-row sum via rotate-add: every lane of the row ends with the row total
__device__ __forceinline__ float row_ror_add(float x){
    x = dpp_add<0x121,0xf,0xf>(x);
    x = dpp_add<0x122,0xf,0xf>(x);
    x = dpp_add<0x124,0xf,0xf>(x);
    x = dpp_add<0x128,0xf,0xf>(x);
    return x;
}

// ---- degree-tiered edge accumulation (NIT*4 edge slots, burst loads) ----
template<int NIT>
__device__ __forceinline__ void edge_fast(const u16* __restrict__ xlin,
        int sAll, int nEdge, int row, int sub4,
        float4 a4, float4 xr4, float4& acc, float& l){
    ushort4 u[NIT];
    #pragma unroll
    for (int i = 0; i < NIT; i++){
        int j = i*4 + row;
        int jc = (j < nEdge) ? j : (nEdge-1);
        int s = __shfl(sAll, jc, 64);
        u[i] = *(const ushort4*)&xlin[((size_t)(unsigned)s << 6) + sub4];
    }
    #pragma unroll
    for (int i = 0; i < NIT; i++){
        float4 xv = bf4(u[i]);
        float v, e;
        v = xv.x + xr4.x; v = fmaxf(v, 0.2f*v); e = v*a4.x;
        v = xv.y + xr4.y; v = fmaxf(v, 0.2f*v); e = fmaf(v, a4.y, e);
        v = xv.z + xr4.z; v = fmaxf(v, 0.2f*v); e = fmaf(v, a4.z, e);
        v = xv.w + xr4.w; v = fmaxf(v, 0.2f*v); e = fmaf(v, a4.w, e);
        e = row_ror_add(e);
        float q = (i*4 + row < nEdge) ? __expf(e) : 0.f;
        l += q;
        acc.x = fmaf(q, xv.x, acc.x);
        acc.y = fmaf(q, xv.y, acc.y);
        acc.z = fmaf(q, xv.z, acc.z);
        acc.w = fmaf(q, xv.w, acc.w);
    }
}

__device__ __forceinline__ void edge_slow(const u16* __restrict__ xlin,
        const int* __restrict__ col, int beg, int deg, int t,
        int sAll, int nEdge, int row, int sub4,
        float4 a4, float4 xr4, float4& acc, float& l){
    for (int j0 = 0; j0 < nEdge; j0 += 4){
        int j = j0 + row;
        int jc = (j < nEdge) ? j : (nEdge-1);
        int s;
        if (jc < 64) s = __shfl(sAll, jc, 64);
        else         s = (jc < deg) ? col[beg + jc] : t;
        float4 xv = bf4(*(const ushort4*)&xlin[((size_t)(unsigned)s << 6) + sub4]);
        float v, e;
        v = xv.x + xr4.x; v = fmaxf(v, 0.2f*v); e = v*a4.x;
        v = xv.y + xr4.y; v = fmaxf(v, 0.2f*v); e = fmaf(v, a4.y, e);
        v = xv.z + xr4.z; v = fmaxf(v, 0.2f*v); e = fmaf(v, a4.z, e);
        v = xv.w + xr4.w; v = fmaxf(v, 0.2f*v); e = fmaf(v, a4.w, e);
        e = row_ror_add(e);
        float q = (j < nEdge) ? __expf(e) : 0.f;
        l += q;
        acc.x = fmaf(q, xv.x, acc.x);
        acc.y = fmaf(q, xv.y, acc.y);
        acc.z = fmaf(q, xv.z, acc.z);
        acc.w = fmaf(q, xv.w, acc.w);
    }
}

// ---------------- CSR build ----------------
__global__ void count_kernel(const int* __restrict__ dst, int* __restrict__ counts, int E){
    int i = blockIdx.x*blockDim.x + threadIdx.x;
    if (i < E) atomicAdd(&counts[dst[i]], 1);
}

__global__ void scan_kernel(const int* __restrict__ counts, int* __restrict__ indptr,
                            int* __restrict__ cursor, int T){
    __shared__ int bufA[1024];
    __shared__ int bufB[1024];
    int tid = threadIdx.x;
    int base = tid * 32;
    int local[32];
    int s = 0;
    #pragma unroll
    for (int i = 0; i < 32; i++){ local[i] = counts[base+i]; s += local[i]; }
    bufA[tid] = s;
    __syncthreads();
    int* src = bufA; int* dst = bufB;
    for (int off = 1; off < 1024; off <<= 1){
        int v = src[tid];
        if (tid >= off) v += src[tid - off];
        dst[tid] = v;
        __syncthreads();
        int* t = src; src = dst; dst = t;
    }
    int excl = src[tid] - s;
    int run = excl;
    #pragma unroll
    for (int i = 0; i < 32; i++){
        indptr[base+i] = run;
        cursor[base+i] = run;
        run += local[i];
    }
    if (tid == 1023) indptr[T] = run;
}

__global__ void scatter_kernel(const int* __restrict__ src, const int* __restrict__ dst,
                               int* __restrict__ cursor, int* __restrict__ col, int E){
    int i = blockIdx.x*blockDim.x + threadIdx.x;
    if (i < E){
        int d = dst[i];
        int pos = atomicAdd(&cursor[d], 1);
        col[pos] = src[i];
    }
}

// ---------------- layer 0 linear + zero-init fused: bf16 xl/xr out ----------------
__global__ void lin0_kernel(const float* __restrict__ x, const float* __restrict__ Wl0,
                            const float* __restrict__ Wr0,
                            u16* __restrict__ xlb, u16* __restrict__ xrb,
                            int* __restrict__ counts, float* __restrict__ muAcc){
    __shared__ float wl[D][FIN+1];
    __shared__ float wr[D][FIN+1];
    __shared__ float xs[32][FIN];
    int tid = threadIdx.x;
    int blk = blockIdx.x;
    int gidx = blk*256 + tid;
    if (gidx < T_NODES) counts[gidx] = 0;             // fused zero
    if (gidx < BGR*D)   muAcc[gidx] = 0.f;
    int rowBase = (blk & 7)*4096 + (blk >> 3)*32;     // XCD swizzle
    for (int i = tid; i < D*FIN; i += 256){
        wl[i>>3][i&7] = Wl0[i];
        wr[i>>3][i&7] = Wr0[i];
    }
    xs[tid>>3][tid&7] = x[rowBase*FIN + tid];
    __syncthreads();
    int wave = tid >> 6, lane = tid & 63;
    int rb = rowBase + wave*8;
    #pragma unroll
    for (int r = 0; r < 8; r++){
        float al = 0.f, ar = 0.f;
        int lr = wave*8 + r;
        #pragma unroll
        for (int k = 0; k < FIN; k++){
            float xv = xs[lr][k];
            al = fmaf(xv, wl[lane][k], al);
            ar = fmaf(xv, wr[lane][k], ar);
        }
        xlb[(size_t)(rb+r)*D + lane] = f2bf(al);
        xrb[(size_t)(rb+r)*D + lane] = f2bf(ar);
    }
}

// ---------------- fused edge+lin, 32 nodes/block (grid 1024 -> 4 blk/CU) ----------
// LDS: hs fp32 (8.7 KB) + bf16 weights (2 x 8.7 KB) = 26 KB -> occupancy grid-bound.
__global__ __launch_bounds__(256) void el_kernel(
        const u16* __restrict__ xlin, const u16* __restrict__ xrin,
        const float* __restrict__ att, const float* __restrict__ bias,
        const int* __restrict__ indptr, const int* __restrict__ col,
        const float* __restrict__ Wl, const float* __restrict__ Wr,
        u16* __restrict__ xlout, u16* __restrict__ xrout, int E){
    __shared__ __align__(16) float hs[32][68];
    __shared__ __align__(16) u16 wls[D][68];
    __shared__ __align__(16) u16 wrs[D][68];
    int tid = threadIdx.x, blk = blockIdx.x;
    int rowBase = (blk & 7)*4096 + (blk >> 3)*32;     // XCD swizzle
    for (int i = tid; i < D*D; i += 256){             // stage weights (bf16 in LDS)
        wls[i>>6][i&63] = f2bf(Wl[i]);
        wrs[i>>6][i&63] = f2bf(Wr[i]);
    }
    int wave = tid >> 6, lane = tid & 63;
    int row = lane >> 4, sub4 = (lane & 15) << 2;
    float4 a4 = *(const float4*)&att[sub4];
    float4 b4 = *(const float4*)&bias[sub4];
    for (int n = 0; n < 8; n++){                      // 8 nodes per wave
        int ln = wave*8 + n;
        int t  = rowBase + ln;
        float4 xr4 = bf4(*(const ushort4*)&xrin[((size_t)t << 6) + sub4]);
        int beg = indptr[t], end = indptr[t+1];
        int deg = end - beg;
        int idx = beg + lane; idx = idx < E ? idx : E - 1;
        int sAll = (lane < deg) ? col[idx] : t;
        int nEdge = deg + 1;
        float4 acc = make_float4(0.f,0.f,0.f,0.f);
        float l = 0.f;
        if      (nEdge <= 16) edge_fast<4>(xlin, sAll, nEdge, row, sub4, a4, xr4, acc, l);
        else if (nEdge <= 24) edge_fast<6>(xlin, sAll, nEdge, row, sub4, a4, xr4, acc, l);
        else if (nEdge <= 32) edge_fast<8>(xlin, sAll, nEdge, row, sub4, a4, xr4, acc, l);
        else edge_slow(xlin, col, beg, deg, t, sAll, nEdge, row, sub4, a4, xr4, acc, l);
        #pragma unroll
        for (int o = 16; o < 64; o <<= 1){
            acc.x += __shfl_xor(acc.x, o, 64);
            acc.y += __shfl_xor(acc.y, o, 64);
            acc.z += __shfl_xor(acc.z, o, 64);
            acc.w += __shfl_xor(acc.w, o, 64);
            l     += __shfl_xor(l,     o, 64);
        }
        if (row == 0){
            float4 hv;
            hv.x = fmaxf(acc.x / l + b4.x, 0.f);      // relu (input to lin)
            hv.y = fmaxf(acc.y / l + b4.y, 0.f);
            hv.z = fmaxf(acc.z / l + b4.z, 0.f);
            hv.w = fmaxf(acc.w / l + b4.w, 0.f);
            *(float4*)&hs[ln][sub4] = hv;
        }
    }
    __syncthreads();
    // ---- lin phase: 32x64 tile, each thread 2 rows x 4 cols x {Wl,Wr} ----
    int ty = tid >> 4, tx = tid & 15;
    int r0 = ty * 2;
    float accl[2][4], accr[2][4];
    #pragma unroll
    for (int i = 0; i < 2; i++)
        #pragma unroll
        for (int j = 0; j < 4; j++){ accl[i][j] = 0.f; accr[i][j] = 0.f; }
    for (int k = 0; k < D; k += 4){
        float4 hv[2], wlv[4], wrv[4];
        #pragma unroll
        for (int i = 0; i < 2; i++)
            hv[i] = *(const float4*)&hs[r0+i][k];
        #pragma unroll
        for (int j = 0; j < 4; j++){
            wlv[j] = bf4(*(const ushort4*)&wls[tx + 16*j][k]);
            wrv[j] = bf4(*(const ushort4*)&wrs[tx + 16*j][k]);
        }
        #pragma unroll
        for (int i = 0; i < 2; i++){
            #pragma unroll
            for (int j = 0; j < 4; j++){
                accl[i][j] += hv[i].x*wlv[j].x + hv[i].y*wlv[j].y
                            + hv[i].z*wlv[j].z + hv[i].w*wlv[j].w;
                accr[i][j] += hv[i].x*wrv[j].x + hv[i].y*wrv[j].y
                            + hv[i].z*wrv[j].z + hv[i].w*wrv[j].w;
            }
        }
    }
    #pragma unroll
    for (int i = 0; i < 2; i++){
        size_t rowOff = (size_t)(rowBase + r0 + i) * D;
        #pragma unroll
        for (int j = 0; j < 4; j++){
            xlout[rowOff + tx + 16*j] = f2bf(accl[i][j]);
            xrout[rowOff + tx + 16*j] = f2bf(accr[i][j]);
        }
    }
}

// ---------------- last edge layer: bf16 in, fp32 h out + graph-mean ----------------
__global__ __launch_bounds__(256) void e4_kernel(
        const u16* __restrict__ xlin, const u16* __restrict__ xrin,
        const float* __restrict__ att, const float* __restrict__ bias,
        const int* __restrict__ indptr, const int* __restrict__ col,
        float* __restrict__ hout, float* __restrict__ muAcc, int E){
    int wave = threadIdx.x >> 6, lane = threadIdx.x & 63;
    int blk = blockIdx.x;
    int t = (blk & 7)*4096 + (blk >> 3)*4 + wave;
    int row = lane >> 4, sub4 = (lane & 15) << 2;
    float4 a4 = *(const float4*)&att[sub4];
    float4 xr4 = bf4(*(const ushort4*)&xrin[((size_t)t << 6) + sub4]);
    int beg = indptr[t], end = indptr[t+1];
    int deg = end - beg;
    int idx = beg + lane; idx = idx < E ? idx : E - 1;
    int sAll = (lane < deg) ? col[idx] : t;
    int nEdge = deg + 1;
    float4 acc = make_float4(0.f,0.f,0.f,0.f);
    float l = 0.f;
    if      (nEdge <= 16) edge_fast<4>(xlin, sAll, nEdge, row, sub4, a4, xr4, acc, l);
    else if (nEdge <= 24) edge_fast<6>(xlin, sAll, nEdge, row, sub4, a4, xr4, acc, l);
    else if (nEdge <= 32) edge_fast<8>(xlin, sAll, nEdge, row, sub4, a4, xr4, acc, l);
    else edge_slow(xlin, col, beg, deg, t, sAll, nEdge, row, sub4, a4, xr4, acc, l);
    #pragma unroll
    for (int o = 16; o < 64; o <<= 1){
        acc.x += __shfl_xor(acc.x, o, 64);
        acc.y += __shfl_xor(acc.y, o, 64);
        acc.z += __shfl_xor(acc.z, o, 64);
        acc.w += __shfl_xor(acc.w, o, 64);
        l     += __shfl_xor(l,     o, 64);
    }
    float4 b4 = *(const float4*)&bias[sub4];
    float4 hv;
    hv.x = acc.x / l + b4.x;                          // NO relu (final h)
    hv.y = acc.y / l + b4.y;
    hv.z = acc.z / l + b4.z;
    hv.w = acc.w / l + b4.w;
    if (row == 0)
        *(float4*)&hout[(size_t)t*D + sub4] = hv;
    __shared__ float red[4][D];
    if (row == 0) *(float4*)&red[wave][sub4] = hv;
    __syncthreads();
    if (wave == 0){
        float s = red[0][lane] + red[1][lane] + red[2][lane] + red[3][lane];
        atomicAdd(&muAcc[(t >> 10)*D + lane], s);
    }
}

// ---------------- per-node head with inlined per-graph pool ----------------
__global__ __launch_bounds__(256) void final_kernel(const float* __restrict__ h,
                             const float* __restrict__ muAcc,
                             const float* __restrict__ t6w, const float* __restrict__ t6b,
                             const float* __restrict__ t7w, const float* __restrict__ t7b,
                             const float* __restrict__ t5pw, const float* __restrict__ t5pb,
                             const float* __restrict__ t5vw, const float* __restrict__ t5vb,
                             const float* __restrict__ pw, const float* __restrict__ pb,
                             const int* __restrict__ reachable,
                             float* __restrict__ out_logits, float* __restrict__ qbuf){
    __shared__ __align__(16) float hs[D][68];
    __shared__ __align__(16) float ws[D][68];
    __shared__ float ppar[D][17];
    __shared__ float qpar[D][17];
    __shared__ float PgQg[2];
    int tid = threadIdx.x;
    int blk = blockIdx.x;
    int rowBase = (blk & 7)*4096 + (blk >> 3)*64;
    int b = rowBase >> 10;
    for (int i = tid; i < D*D; i += 256) ws[i>>6][i&63] = t6w[i];
    if (tid < D) hs[0][tid] = muAcc[b*D + tid] * (1.f/NPG);
    __syncthreads();
    if (tid < D){
        int d = tid;
        float g = t6b[d];
        #pragma unroll
        for (int k = 0; k < D; k++) g = fmaf(hs[0][k], ws[d][k], g);
        g = fmaxf(g, 0.f);
        float pp = wave_sum_bcast(g * t5pw[d]);
        float qq = wave_sum_bcast(g * t5vw[d]);
        if (d == 0){ PgQg[0] = pp; PgQg[1] = qq; }
    }
    __syncthreads();
    for (int i = tid; i < D*D; i += 256){
        int r = i >> 6, c = i & 63;
        hs[r][c] = h[(size_t)rowBase*D + i];
        ws[r][c] = t7w[i];
    }
    __syncthreads();
    int ty = tid >> 4, tx = tid & 15;
    int r0 = ty * 4;
    float acc[4][4];
    #pragma unroll
    for (int i = 0; i < 4; i++)
        #pragma unroll
        for (int j = 0; j < 4; j++) acc[i][j] = 0.f;
    for (int k = 0; k < D; k += 4){
        float4 hv[4], wv[4];
        #pragma unroll
        for (int i = 0; i < 4; i++){
            hv[i] = *(const float4*)&hs[r0+i][k];
            wv[i] = *(const float4*)&ws[tx + 16*i][k];
        }
        #pragma unroll
        for (int i = 0; i < 4; i++)
            #pragma unroll
            for (int j = 0; j < 4; j++)
                acc[i][j] += hv[i].x*wv[j].x + hv[i].y*wv[j].y
                           + hv[i].z*wv[j].z + hv[i].w*wv[j].w;
    }
    float bc[4], pwc[4], qwc[4];
    #pragma unroll
    for (int j = 0; j < 4; j++){
        int c = tx + 16*j;
        bc[j]  = t7b[c];
        pwc[j] = t5pw[D + c];
        qwc[j] = t5vw[D + c];
    }
    #pragma unroll
    for (int i = 0; i < 4; i++){
        float sp = 0.f, sq = 0.f;
        #pragma unroll
        for (int j = 0; j < 4; j++){
            float lv = fmaxf(acc[i][j] + bc[j], 0.f);
            sp = fmaf(lv, pwc[j], sp);
            sq = fmaf(lv, qwc[j], sq);
        }
        ppar[r0+i][tx] = sp;
        qpar[r0+i][tx] = sq;
    }
    __syncthreads();
    if (tid < 64){
        int t = rowBase + tid;
        float sp = 0.f, sq = 0.f;
        #pragma unroll
        for (int c = 0; c < 16; c++){ sp += ppar[tid][c]; sq += qpar[tid][c]; }
        float prob = PgQg[0] + sp + t5pb[0];
        out_logits[t] = prob * pw[0] + pb[0];
        float q = PgQg[1] + sq + t5vb[0];
        if (!reachable[t]) q = -1e20f;
        qbuf[t] = q;
    }
}

// ---------------- per-graph masked max -> value ----------------
__global__ void value_kernel(const float* __restrict__ qbuf, const float* __restrict__ vw,
                             const float* __restrict__ vb, float* __restrict__ out_value){
    __shared__ float part[256];
    int b = blockIdx.x, tid = threadIdx.x;
    float m = -INFINITY;
    for (int i = tid; i < NPG; i += 256) m = fmaxf(m, qbuf[b*NPG + i]);
    part[tid] = m;
    __syncthreads();
    for (int s = 128; s > 0; s >>= 1){
        if (tid < s) part[tid] = fmaxf(part[tid], part[tid+s]);
        __syncthreads();
    }
    if (tid == 0) out_value[b] = part[0]*vw[0] + vb[0];
}

extern "C" void kernel_launch(void* const* d_in, const int* in_sizes, int n_in,
                              void* d_out, int out_size, void* d_ws, size_t ws_size,
                              hipStream_t stream){
    const float* x          = (const float*)d_in[0];
    const int*   edge_index = (const int*)d_in[1];
    const int*   reachable  = (const int*)d_in[2];
    const float* Wl0 = (const float*)d_in[3];
    const float* Wr0 = (const float*)d_in[4];
    const float* att0= (const float*)d_in[5];
    const float* b0  = (const float*)d_in[6];
    const float* Wl  = (const float*)d_in[7];
    const float* Wr  = (const float*)d_in[8];
    const float* att = (const float*)d_in[9];
    const float* bb  = (const float*)d_in[10];
    const float* t6w = (const float*)d_in[11];
    const float* t6b = (const float*)d_in[12];
    const float* t7w = (const float*)d_in[13];
    const float* t7b = (const float*)d_in[14];
    const float* t5pw= (const float*)d_in[15];
    const float* t5pb= (const float*)d_in[16];
    const float* t5vw= (const float*)d_in[17];
    const float* t5vb= (const float*)d_in[18];
    const float* pw  = (const float*)d_in[19];
    const float* pb  = (const float*)d_in[20];
    const float* vw  = (const float*)d_in[21];
    const float* vb  = (const float*)d_in[22];

    int E = in_sizes[1] / 2;
    const int* esrc = edge_index;
    const int* edst = edge_index + E;

    char* ws = (char*)d_ws;
    float* h    = (float*)(ws);
    u16* xlbA   = (u16*)(ws + (size_t)T_NODES*D*4);
    u16* xrbA   = (u16*)((char*)xlbA + (size_t)T_NODES*D*2);
    u16* xlbB   = (u16*)((char*)xrbA + (size_t)T_NODES*D*2);
    u16* xrbB   = (u16*)((char*)xlbB + (size_t)T_NODES*D*2);
    int* counts = (int*)((char*)xrbB + (size_t)T_NODES*D*2);
    int* indptr = (int*)((char*)counts + (size_t)(T_NODES+16)*4);
    int* cursor = (int*)((char*)indptr + (size_t)(T_NODES+16)*4);
    int* col    = (int*)((char*)cursor + (size_t)(T_NODES+16)*4);
    float* qbuf = (float*)((char*)col + (size_t)(E+64)*4);
    float* muAcc= (float*)((char*)qbuf + (size_t)T_NODES*4);

    lin0_kernel<<<T_NODES/32, 256, 0, stream>>>(x, Wl0, Wr0, xlbA, xrbA, counts, muAcc);
    count_kernel<<<(E+255)/256, 256, 0, stream>>>(edst, counts, E);
    scan_kernel<<<1, 1024, 0, stream>>>(counts, indptr, cursor, T_NODES);
    scatter_kernel<<<(E+255)/256, 256, 0, stream>>>(esrc, edst, cursor, col, E);

    // EL_i: edge of layer i (+relu) then lin with Wl[i]/Wr[i]; ping-pong A/B
    el_kernel<<<T_NODES/32, 256, 0, stream>>>(xlbA, xrbA, att0, b0, indptr, col,
                                              Wl + 0*D*D, Wr + 0*D*D, xlbB, xrbB, E);
    el_kernel<<<T_NODES/32, 256, 0, stream>>>(xlbB, xrbB, att + 0*D, bb + 0*D, indptr, col,
                                              Wl + 1*D*D, Wr + 1*D*D, xlbA, xrbA, E);
    el_kernel<<<T_NODES/32, 256, 0, stream>>>(xlbA, xrbA, att + 1*D, bb + 1*D, indptr, col,
                                              Wl + 2*D*D, Wr + 2*D*D, xlbB, xrbB, E);
    el_kernel<<<T_NODES/32, 256, 0, stream>>>(xlbB, xrbB, att + 2*D, bb + 2*D, indptr, col,
                                              Wl + 3*D*D, Wr + 3*D*D, xlbA, xrbA, E);
    e4_kernel<<<T_NODES/4, 256, 0, stream>>>(xlbA, xrbA, att + 3*D, bb + 3*D, indptr, col,
                                             h, muAcc, E);

    final_kernel<<<T_NODES/64, 256, 0, stream>>>(h, muAcc, t6w, t6b, t7w, t7b,
                                                 t5pw, t5pb, t5vw, t5vb, pw, pb,
                                                 reachable, (float*)d_out, qbuf);
    value_kernel<<<BGR, 256, 0, stream>>>(qbuf, vw, vb, (float*)d_out + T_NODES);
}